// Round 2
// baseline (681.145 us; speedup 1.0000x reference)
//
#include <hip/hip_runtime.h>
#include <stdint.h>

#define B_ 4
#define C_ 512
#define CQ_ 64
#define H_ 128
#define W_ 128
#define HW_ 16384

typedef unsigned short u16;
typedef unsigned int u32;
typedef __attribute__((ext_vector_type(8))) __bf16 bf16x8;
typedef __attribute__((ext_vector_type(4))) float f32x4;

union BF8 { bf16x8 v; u16 s[8]; u32 u[4]; };

__device__ __forceinline__ u16 f2bf(float f) {
    u32 v; __builtin_memcpy(&v, &f, 4);
    v = (v + 0x7FFFu + ((v >> 16) & 1u)) >> 16;
    return (u16)v;
}
__device__ __forceinline__ float bf2f(u16 a) {
    u32 v = ((u32)a) << 16; float f; __builtin_memcpy(&f, &v, 4); return f;
}

// workspace element offsets (bf16 elements)
#define WS_Q   0u
#define WS_K   4194304u
#define WS_V   8388608u
#define WS_QT  41943040u
#define WS_KT  46137344u
#define WS_VT  50331648u
#define WS_CV  83886080u
// total ws need: 117,440,512 bf16 elems = 234,881,024 bytes

// ---------------------------------------------------------------------------
// Kernel 1: projection GEMM.  out[o][p] = sum_c W[o][c] * x[b][c][p] + bias[o]
// M=640 (10 tiles of 64: tile0=Wq, tile1=Wk, tiles2..9=Wv), N=16384/batch, K=512
// x, W, bias are f32; q/k/v written to ws as bf16.
// ---------------------------------------------------------------------------
__global__ __launch_bounds__(256) void proj_kernel(
    const float* __restrict__ x, const float* __restrict__ Wq, const float* __restrict__ bq,
    const float* __restrict__ Wk, const float* __restrict__ bk,
    const float* __restrict__ Wv, const float* __restrict__ bv, u16* __restrict__ ws)
{
    __shared__ __align__(16) u16 As[64][72];   // [o][c] bf16, 144B rows
    __shared__ __align__(16) u16 Bs[64][66];   // x^T tile: [p][c] bf16, 132B rows
    const int t = threadIdx.x;
    const int bm = blockIdx.x, bn = blockIdx.y, b = blockIdx.z;
    const int p0 = bn * 64;

    const float* Wsrc; const float* bias; u16* dst;
    if (bm == 0)      { Wsrc = Wq;                 bias = bq;             dst = ws + WS_Q + (u32)(b*CQ_)*HW_; }
    else if (bm == 1) { Wsrc = Wk;                 bias = bk;             dst = ws + WS_K + (u32)(b*CQ_)*HW_; }
    else              { Wsrc = Wv + (bm-2)*64*C_;  bias = bv + (bm-2)*64; dst = ws + WS_V + ((u32)(b*C_) + (bm-2)*64)*HW_; }
    const float* xb = x + (u32)(b*C_)*HW_;

    const int wv = t >> 6, ln = t & 63, quad = ln >> 4, col = ln & 15;
    f32x4 acc[4];
    #pragma unroll
    for (int nt = 0; nt < 4; ++nt) acc[nt] = (f32x4){0.f, 0.f, 0.f, 0.f};

    for (int c0 = 0; c0 < C_; c0 += 64) {
        // stage A: W[64 o][64 c] f32 -> bf16
        {
            int row = t >> 4, cg = t & 15;
            #pragma unroll
            for (int pass = 0; pass < 4; ++pass, row += 16) {
                float4 d = *reinterpret_cast<const float4*>(Wsrc + row*C_ + c0 + cg*4);
                u16 e[4] = { f2bf(d.x), f2bf(d.y), f2bf(d.z), f2bf(d.w) };
                *reinterpret_cast<uint2*>(&As[row][cg*4]) = *reinterpret_cast<const uint2*>(e);
            }
        }
        // stage B transposed: Bs[p][c], x f32 -> bf16
        {
            int cl = t >> 4, pg = t & 15;
            #pragma unroll
            for (int pass = 0; pass < 4; ++pass, cl += 16) {
                float4 d = *reinterpret_cast<const float4*>(xb + (u32)(c0+cl)*HW_ + p0 + pg*4);
                Bs[pg*4+0][cl] = f2bf(d.x);
                Bs[pg*4+1][cl] = f2bf(d.y);
                Bs[pg*4+2][cl] = f2bf(d.z);
                Bs[pg*4+3][cl] = f2bf(d.w);
            }
        }
        __syncthreads();
        #pragma unroll
        for (int ks = 0; ks < 2; ++ks) {
            const int kk = ks * 32;
            bf16x8 af = *reinterpret_cast<const bf16x8*>(&As[wv*16 + col][kk + quad*8]);
            #pragma unroll
            for (int nt = 0; nt < 4; ++nt) {
                BF8 bf;
                const int prow = nt*16 + col;
                #pragma unroll
                for (int jj = 0; jj < 4; ++jj)
                    bf.u[jj] = *reinterpret_cast<const u32*>(&Bs[prow][kk + quad*8 + jj*2]);
                acc[nt] = __builtin_amdgcn_mfma_f32_16x16x32_bf16(af, bf.v, acc[nt], 0, 0, 0);
            }
        }
        __syncthreads();
    }
    // epilogue: D[row=(quad*4+r)][col=lane&15]
    #pragma unroll
    for (int r = 0; r < 4; ++r) {
        const int ol = wv*16 + quad*4 + r;
        const float bb = bias[ol];
        #pragma unroll
        for (int nt = 0; nt < 4; ++nt) {
            const int pl = nt*16 + col;
            dst[(u32)ol*HW_ + p0 + pl] = f2bf(acc[nt][r] + bb);
        }
    }
}

// ---------------------------------------------------------------------------
// Kernel 2: transpose q,k,v  [img][h][w] -> [img][w][h]  (img = 2560 channel-images, bf16)
// ---------------------------------------------------------------------------
__global__ __launch_bounds__(256) void transpose_kernel(u16* __restrict__ ws)
{
    __shared__ u16 tl[64][66];
    const int t = threadIdx.x;
    const int tile = blockIdx.x, img = blockIdx.y;
    const int h0 = (tile >> 1) * 64, w0 = (tile & 1) * 64;
    const u16* src = ws + (u32)img * HW_;
    u16* dst = ws + WS_QT + (u32)img * HW_;
    for (int e = t; e < 4096; e += 256) { int hl = e >> 6, wl = e & 63; tl[hl][wl] = src[(h0+hl)*W_ + w0 + wl]; }
    __syncthreads();
    for (int e = t; e < 4096; e += 256) { int wl = e >> 6, hl = e & 63; dst[(w0+wl)*H_ + h0 + hl] = tl[hl][wl]; }
}

// shared LDS for attention kernels: q/k staging overlapped with softmaxed A
union __align__(16) ShAttn {
    struct QK { u16 q[128][72]; u16 kt[128][72]; } qk;  // 36864 B
    u16 a[128][136];                                    // 34816 B
};

// ---------------------------------------------------------------------------
// Kernel 3: horizontal attention, one block per (b,h). Writes raw ch (f32) -> d_out.
// S[w1][w2] = sum_i q[w1][i] * kh[i][w2],  kh[i][w2] = k[w2&63][2i + (w2>>6)]
// ch[cc][w1] = sum_w2 A[w1][w2] * v[cc][w2]
// ---------------------------------------------------------------------------
__global__ __launch_bounds__(256) void hattn_kernel(const u16* __restrict__ ws, float* __restrict__ outp)
{
    __shared__ ShAttn sh;
    const int t = threadIdx.x;
    const int h = blockIdx.x, b = blockIdx.y;
    const u16* qsrc = ws + WS_Q + (u32)(b*CQ_)*HW_ + h*W_;
    const u16* ksrc = ws + WS_K + (u32)(b*CQ_)*HW_ + h*W_;

    for (int e = t; e < 8192; e += 256) {
        int cq = e >> 7, w = e & 127;
        sh.qk.q[w][cq] = qsrc[cq*HW_ + w];
        u16 kv = ksrc[cq*HW_ + w];
        sh.qk.kt[cq + ((w & 1) << 6)][w >> 1] = kv;   // kt[w2][i] = kh[i][w2]
    }
    __syncthreads();

    const int wv = t >> 6, ln = t & 63, quad = ln >> 4, col = ln & 15;
    f32x4 accs[2][8];
    #pragma unroll
    for (int mt = 0; mt < 2; ++mt)
        #pragma unroll
        for (int nt = 0; nt < 8; ++nt) accs[mt][nt] = (f32x4){0.f,0.f,0.f,0.f};

    #pragma unroll
    for (int ks = 0; ks < 2; ++ks) {
        bf16x8 bfv[8];
        #pragma unroll
        for (int nt = 0; nt < 8; ++nt)
            bfv[nt] = *reinterpret_cast<const bf16x8*>(&sh.qk.kt[nt*16 + col][ks*32 + quad*8]);
        #pragma unroll
        for (int mt = 0; mt < 2; ++mt) {
            bf16x8 af = *reinterpret_cast<const bf16x8*>(&sh.qk.q[(wv*2 + mt)*16 + col][ks*32 + quad*8]);
            #pragma unroll
            for (int nt = 0; nt < 8; ++nt)
                accs[mt][nt] = __builtin_amdgcn_mfma_f32_16x16x32_bf16(af, bfv[nt], accs[mt][nt], 0, 0, 0);
        }
    }
    // softmax per row (row r of quad lives in the 16 lanes sharing quad)
    #pragma unroll
    for (int mt = 0; mt < 2; ++mt) {
        #pragma unroll
        for (int r = 0; r < 4; ++r) {
            float mx = accs[mt][0][r];
            #pragma unroll
            for (int nt = 1; nt < 8; ++nt) mx = fmaxf(mx, accs[mt][nt][r]);
            #pragma unroll
            for (int d = 1; d <= 8; d <<= 1) mx = fmaxf(mx, __shfl_xor(mx, d, 64));
            float sum = 0.f;
            #pragma unroll
            for (int nt = 0; nt < 8; ++nt) { float ev = __expf(accs[mt][nt][r] - mx); accs[mt][nt][r] = ev; sum += ev; }
            #pragma unroll
            for (int d = 1; d <= 8; d <<= 1) sum += __shfl_xor(sum, d, 64);
            float inv = 1.f / sum;
            #pragma unroll
            for (int nt = 0; nt < 8; ++nt) accs[mt][nt][r] *= inv;
        }
    }
    __syncthreads();  // all waves done reading q/kt
    #pragma unroll
    for (int mt = 0; mt < 2; ++mt)
        #pragma unroll
        for (int nt = 0; nt < 8; ++nt)
            #pragma unroll
            for (int r = 0; r < 4; ++r) {
                int w1 = (wv*2 + mt)*16 + quad*4 + r;
                int w2 = nt*16 + col;
                sh.a[w1][w2] = f2bf(accs[mt][nt][r]);
            }
    __syncthreads();

    // A@V: D[cc][w1] = sum_w2 V[cc][w2] * A[w1][w2]; A-op = V (global 16B), B-op = A^T (LDS)
    const u16* vsrc = ws + WS_V + (u32)(b*C_)*HW_ + h*W_;
    float* chout = outp + (u32)(b*C_)*HW_ + h*W_;
    const int ccw = wv * 128;
    for (int mp = 0; mp < 4; ++mp) {
        f32x4 accv[2][8];
        #pragma unroll
        for (int mi = 0; mi < 2; ++mi)
            #pragma unroll
            for (int nt = 0; nt < 8; ++nt) accv[mi][nt] = (f32x4){0.f,0.f,0.f,0.f};
        #pragma unroll
        for (int ks = 0; ks < 4; ++ks) {
            bf16x8 bfv[8];
            #pragma unroll
            for (int nt = 0; nt < 8; ++nt)
                bfv[nt] = *reinterpret_cast<const bf16x8*>(&sh.a[nt*16 + col][ks*32 + quad*8]);
            #pragma unroll
            for (int mi = 0; mi < 2; ++mi) {
                int cct = ccw + (mp*2 + mi)*16;
                bf16x8 af = *reinterpret_cast<const bf16x8*>(&vsrc[(u32)(cct + col)*HW_ + ks*32 + quad*8]);
                #pragma unroll
                for (int nt = 0; nt < 8; ++nt)
                    accv[mi][nt] = __builtin_amdgcn_mfma_f32_16x16x32_bf16(af, bfv[nt], accv[mi][nt], 0, 0, 0);
            }
        }
        #pragma unroll
        for (int mi = 0; mi < 2; ++mi)
            #pragma unroll
            for (int nt = 0; nt < 8; ++nt)
                #pragma unroll
                for (int r = 0; r < 4; ++r) {
                    int cc = ccw + (mp*2 + mi)*16 + quad*4 + r;
                    int w1 = nt*16 + col;
                    chout[(u32)cc*HW_ + w1] = accv[mi][nt][r];
                }
    }
}

// ---------------------------------------------------------------------------
// Kernel 4: vertical attention, one block per (b,w). Writes cvT[b][cc][w][h1] (bf16) to ws.
// qv[h1][i] = qT[h1>>1][w][64*(h1&1)+i];  kv[i][h2] = kT[i][w][h2]
// vv[h2][cc] = vT[4*h2+(cc>>7)][w][cc&127]
// ---------------------------------------------------------------------------
__global__ __launch_bounds__(256) void vattn_kernel(u16* __restrict__ ws)
{
    __shared__ ShAttn sh;
    const int t = threadIdx.x;
    const int w = blockIdx.x, b = blockIdx.y;
    const u16* qTs = ws + WS_QT + (u32)(b*CQ_)*HW_ + w*H_;
    const u16* kTs = ws + WS_KT + (u32)(b*CQ_)*HW_ + w*H_;

    for (int e = t; e < 8192; e += 256) {
        int cq = e >> 7, hh = e & 127;
        sh.qk.q[2*cq + (hh >> 6)][hh & 63] = qTs[cq*HW_ + hh];   // qv[h1][i]
        sh.qk.kt[hh][cq] = kTs[cq*HW_ + hh];                      // kt[h2][i] = kv[i][h2]
    }
    __syncthreads();

    const int wv = t >> 6, ln = t & 63, quad = ln >> 4, col = ln & 15;
    f32x4 accs[2][8];
    #pragma unroll
    for (int mt = 0; mt < 2; ++mt)
        #pragma unroll
        for (int nt = 0; nt < 8; ++nt) accs[mt][nt] = (f32x4){0.f,0.f,0.f,0.f};

    #pragma unroll
    for (int ks = 0; ks < 2; ++ks) {
        bf16x8 bfv[8];
        #pragma unroll
        for (int nt = 0; nt < 8; ++nt)
            bfv[nt] = *reinterpret_cast<const bf16x8*>(&sh.qk.kt[nt*16 + col][ks*32 + quad*8]);
        #pragma unroll
        for (int mt = 0; mt < 2; ++mt) {
            bf16x8 af = *reinterpret_cast<const bf16x8*>(&sh.qk.q[(wv*2 + mt)*16 + col][ks*32 + quad*8]);
            #pragma unroll
            for (int nt = 0; nt < 8; ++nt)
                accs[mt][nt] = __builtin_amdgcn_mfma_f32_16x16x32_bf16(af, bfv[nt], accs[mt][nt], 0, 0, 0);
        }
    }
    #pragma unroll
    for (int mt = 0; mt < 2; ++mt) {
        #pragma unroll
        for (int r = 0; r < 4; ++r) {
            float mx = accs[mt][0][r];
            #pragma unroll
            for (int nt = 1; nt < 8; ++nt) mx = fmaxf(mx, accs[mt][nt][r]);
            #pragma unroll
            for (int d = 1; d <= 8; d <<= 1) mx = fmaxf(mx, __shfl_xor(mx, d, 64));
            float sum = 0.f;
            #pragma unroll
            for (int nt = 0; nt < 8; ++nt) { float ev = __expf(accs[mt][nt][r] - mx); accs[mt][nt][r] = ev; sum += ev; }
            #pragma unroll
            for (int d = 1; d <= 8; d <<= 1) sum += __shfl_xor(sum, d, 64);
            float inv = 1.f / sum;
            #pragma unroll
            for (int nt = 0; nt < 8; ++nt) accs[mt][nt][r] *= inv;
        }
    }
    __syncthreads();
    #pragma unroll
    for (int mt = 0; mt < 2; ++mt)
        #pragma unroll
        for (int nt = 0; nt < 8; ++nt)
            #pragma unroll
            for (int r = 0; r < 4; ++r) {
                int h1 = (wv*2 + mt)*16 + quad*4 + r;
                int h2 = nt*16 + col;
                sh.a[h1][h2] = f2bf(accs[mt][nt][r]);
            }
    __syncthreads();

    const u16* vTs = ws + WS_VT + (u32)(b*C_)*HW_ + w*H_;
    u16* cvout = ws + WS_CV + (u32)(b*C_)*HW_ + w*H_;
    const int ccw = wv * 128;
    for (int mp = 0; mp < 4; ++mp) {
        f32x4 accv[2][8];
        #pragma unroll
        for (int mi = 0; mi < 2; ++mi)
            #pragma unroll
            for (int nt = 0; nt < 8; ++nt) accv[mi][nt] = (f32x4){0.f,0.f,0.f,0.f};
        #pragma unroll
        for (int ks = 0; ks < 4; ++ks) {
            bf16x8 bfv[8];
            #pragma unroll
            for (int nt = 0; nt < 8; ++nt)
                bfv[nt] = *reinterpret_cast<const bf16x8*>(&sh.a[nt*16 + col][ks*32 + quad*8]);
            #pragma unroll
            for (int mi = 0; mi < 2; ++mi) {
                int cct = ccw + (mp*2 + mi)*16;
                int chi = cct >> 7;
                int clo = (cct & 127) + col;
                BF8 af;
                #pragma unroll
                for (int jj = 0; jj < 8; ++jj) {
                    int h2 = ks*32 + quad*8 + jj;
                    af.s[jj] = vTs[(u32)(4*h2 + chi)*HW_ + clo];
                }
                #pragma unroll
                for (int nt = 0; nt < 8; ++nt)
                    accv[mi][nt] = __builtin_amdgcn_mfma_f32_16x16x32_bf16(af.v, bfv[nt], accv[mi][nt], 0, 0, 0);
            }
        }
        #pragma unroll
        for (int mi = 0; mi < 2; ++mi)
            #pragma unroll
            for (int nt = 0; nt < 8; ++nt)
                #pragma unroll
                for (int r = 0; r < 4; ++r) {
                    int cc = ccw + (mp*2 + mi)*16 + quad*4 + r;
                    int h1 = nt*16 + col;
                    cvout[(u32)cc*HW_ + h1] = f2bf(accv[mi][nt][r]);
                }
    }
}

// ---------------------------------------------------------------------------
// Kernel 5: out = gamma*(ch + cv) + x  (f32); ch in d_out (f32), cv transposed bf16 in ws
// ---------------------------------------------------------------------------
__global__ __launch_bounds__(256) void combine_kernel(const u16* __restrict__ ws, const float* __restrict__ x,
                                                      const float* __restrict__ gamma, float* __restrict__ outp)
{
    __shared__ u16 tl[64][66];
    const int t = threadIdx.x;
    const int tile = blockIdx.x, cc = blockIdx.y, b = blockIdx.z;
    const int h0 = (tile >> 1) * 64, w0 = (tile & 1) * 64;
    const float g = gamma[0];
    const u32 base = ((u32)(b*C_) + cc) * HW_;
    const u16* cvs = ws + WS_CV + base;
    for (int e = t; e < 4096; e += 256) { int wl = e >> 6, hl = e & 63; tl[wl][hl] = cvs[(w0+wl)*H_ + h0 + hl]; }
    __syncthreads();
    for (int e = t; e < 4096; e += 256) {
        int hl = e >> 6, wl = e & 63;
        u32 idx = base + (h0+hl)*W_ + w0 + wl;
        float cv = bf2f(tl[wl][hl]);
        float ch = outp[idx];
        outp[idx] = g * (ch + cv) + x[idx];
    }
}

extern "C" void kernel_launch(void* const* d_in, const int* in_sizes, int n_in,
                              void* d_out, int out_size, void* d_ws, size_t ws_size,
                              hipStream_t stream)
{
    const float* x  = (const float*)d_in[0];
    const float* Wq = (const float*)d_in[1];
    const float* bq = (const float*)d_in[2];
    const float* Wk = (const float*)d_in[3];
    const float* bk = (const float*)d_in[4];
    const float* Wv = (const float*)d_in[5];
    const float* bv = (const float*)d_in[6];
    const float* gm = (const float*)d_in[7];
    float* out = (float*)d_out;
    u16* ws  = (u16*)d_ws;

    proj_kernel<<<dim3(10, 256, 4), 256, 0, stream>>>(x, Wq, bq, Wk, bk, Wv, bv, ws);
    transpose_kernel<<<dim3(4, 2560), 256, 0, stream>>>(ws);
    hattn_kernel<<<dim3(128, 4), 256, 0, stream>>>(ws, out);
    vattn_kernel<<<dim3(128, 4), 256, 0, stream>>>(ws);
    combine_kernel<<<dim3(4, 512, 4), 256, 0, stream>>>(ws, x, gm, out);
}

// Round 4
// 622.775 us; speedup vs baseline: 1.0937x; 1.0937x over previous
//
#include <hip/hip_runtime.h>
#include <stdint.h>

#define B_ 4
#define C_ 512
#define CQ_ 64
#define H_ 128
#define W_ 128
#define HW_ 16384

typedef unsigned short u16;
typedef unsigned int u32;
typedef __attribute__((ext_vector_type(8))) __bf16 bf16x8;
typedef __attribute__((ext_vector_type(4))) float f32x4;

union BF8 { bf16x8 v; u16 s[8]; u32 u[4]; uint4 q4; };

__device__ __forceinline__ u16 f2bf(float f) {
    u32 v; __builtin_memcpy(&v, &f, 4);
    v = (v + 0x7FFFu + ((v >> 16) & 1u)) >> 16;
    return (u16)v;
}
__device__ __forceinline__ float bf2f(u16 a) {
    u32 v = ((u32)a) << 16; float f; __builtin_memcpy(&f, &v, 4); return f;
}

// ---- workspace map (u16 elements), total 117,440,512 elems = 234,881,024 B ----
// XT (x^T bf16, [b][p][c]) dies after proj; CV reuses its space (vattn runs later).
// WB (W bf16) dies after proj; QT region (written by transpose_qk, post-proj) reuses it.
#define WS_XT  0u
#define WS_CV  0u
#define WS_Q   33554432u
#define WS_K   37748736u
#define WS_V   41943040u   // layout [b][h][c][w]
#define WS_QT  75497472u
#define WS_KT  79691776u
#define WS_WB  75497472u   // aliases QT
#define WS_VT  83886080u   // layout [b][c][w][h]

// ---------------------------------------------------------------------------
// prep_x: x f32 [b][c][p] -> XT bf16 [b][p][c]   (convert once + transpose)
// ---------------------------------------------------------------------------
__global__ __launch_bounds__(256) void prep_x(const float* __restrict__ x, u16* __restrict__ ws)
{
    __shared__ __align__(16) u16 tl[64][72];
    const int t = threadIdx.x;
    const int pt = blockIdx.x, ct = blockIdx.y, b = blockIdx.z;
    const int p0 = pt * 64, c0 = ct * 64;
    const float* xb = x + ((u32)(b*C_ + c0))*HW_ + p0;
    #pragma unroll
    for (int pass = 0; pass < 4; ++pass) {
        int ci = pass*256 + t, cl = ci >> 4, p4 = ci & 15;
        float4 d = *reinterpret_cast<const float4*>(xb + (u32)cl*HW_ + p4*4);
        tl[p4*4+0][cl] = f2bf(d.x); tl[p4*4+1][cl] = f2bf(d.y);
        tl[p4*4+2][cl] = f2bf(d.z); tl[p4*4+3][cl] = f2bf(d.w);
    }
    __syncthreads();
    u16* dst = ws + WS_XT + ((u32)((b<<14) + p0))*512 + c0;
    #pragma unroll
    for (int pass = 0; pass < 2; ++pass) {
        int ci = pass*256 + t, pr = ci >> 3, k8 = ci & 7;
        uint4 d = *reinterpret_cast<const uint4*>(&tl[pr][k8*8]);
        *reinterpret_cast<uint4*>(dst + (u32)pr*512 + k8*8) = d;
    }
}

// ---------------------------------------------------------------------------
// prep_w: concat [Wq;Wk;Wv] f32 -> WB bf16 [640][512]. grid 320, 256 thr.
// ---------------------------------------------------------------------------
__global__ __launch_bounds__(256) void prep_w(const float* __restrict__ Wq, const float* __restrict__ Wk,
                                              const float* __restrict__ Wv, u16* __restrict__ ws)
{
    const int f = (blockIdx.x*256 + threadIdx.x)*4;
    const float* src;
    if (f < 32768)      src = Wq + f;
    else if (f < 65536) src = Wk + (f - 32768);
    else                src = Wv + (f - 65536);
    float4 d = *reinterpret_cast<const float4*>(src);
    u16 e[4] = { f2bf(d.x), f2bf(d.y), f2bf(d.z), f2bf(d.w) };
    *reinterpret_cast<uint2*>(ws + WS_WB + f) = *reinterpret_cast<const uint2*>(e);
}

// ---------------------------------------------------------------------------
// proj: D[o][p] = sum_c WB[o][c]*xT[p][c] (+bias). 128x128 tile, BK=64.
// grid (5 bm, 128 bn(=h), 4 b). q,k -> [b][cq][hw]; v -> [b][h][c][w].
// ---------------------------------------------------------------------------
__global__ __launch_bounds__(256) void proj_kernel(const float* __restrict__ bq, const float* __restrict__ bk,
                                                   const float* __restrict__ bv, u16* __restrict__ ws)
{
    __shared__ __align__(16) u16 As[128][72];
    __shared__ __align__(16) u16 Bs[128][72];
    const int t = threadIdx.x;
    const int bm = blockIdx.x, bn = blockIdx.y, b = blockIdx.z;
    const int m0 = bm*128, p0 = bn*128;
    const u16* WB = ws + WS_WB;
    const u16* XT = ws + WS_XT + ((u32)((b<<14) + p0))*512;
    const int wv = t >> 6, ln = t & 63, quad = ln >> 4, col = ln & 15;
    const int mh = (wv>>1)*64, nh = (wv&1)*64;

    f32x4 acc[4][4];
    #pragma unroll
    for (int mt = 0; mt < 4; ++mt)
        #pragma unroll
        for (int nt = 0; nt < 4; ++nt) acc[mt][nt] = (f32x4){0.f,0.f,0.f,0.f};

    for (int c0 = 0; c0 < 512; c0 += 64) {
        #pragma unroll
        for (int pass = 0; pass < 4; ++pass) {
            int ci = pass*256 + t, row = ci >> 3, k8 = ci & 7;
            uint4 da = *reinterpret_cast<const uint4*>(WB + (u32)(m0+row)*512 + c0 + k8*8);
            *reinterpret_cast<uint4*>(&As[row][k8*8]) = da;
            uint4 db = *reinterpret_cast<const uint4*>(XT + (u32)row*512 + c0 + k8*8);
            *reinterpret_cast<uint4*>(&Bs[row][k8*8]) = db;
        }
        __syncthreads();
        #pragma unroll
        for (int ks = 0; ks < 2; ++ks) {
            const int kk = ks*32 + quad*8;
            bf16x8 am[4], bn_[4];
            #pragma unroll
            for (int mt = 0; mt < 4; ++mt) am[mt]  = *reinterpret_cast<const bf16x8*>(&As[mh + mt*16 + col][kk]);
            #pragma unroll
            for (int nt = 0; nt < 4; ++nt) bn_[nt] = *reinterpret_cast<const bf16x8*>(&Bs[nh + nt*16 + col][kk]);
            #pragma unroll
            for (int mt = 0; mt < 4; ++mt)
                #pragma unroll
                for (int nt = 0; nt < 4; ++nt)
                    acc[mt][nt] = __builtin_amdgcn_mfma_f32_16x16x32_bf16(am[mt], bn_[nt], acc[mt][nt], 0, 0, 0);
        }
        __syncthreads();
    }
    const int h = bn;
    #pragma unroll
    for (int mt = 0; mt < 4; ++mt) {
        const int obase = m0 + mh + mt*16 + quad*4;
        #pragma unroll
        for (int r = 0; r < 4; ++r) {
            const int o = obase + r;
            float bb; u16* dst;
            if (o < 64)       { bb = bq[o];     dst = ws + WS_Q + ((u32)((b<<6) + o))*HW_ + p0; }
            else if (o < 128) { bb = bk[o-64];  dst = ws + WS_K + ((u32)((b<<6) + (o-64)))*HW_ + p0; }
            else              { bb = bv[o-128]; dst = ws + WS_V + (u32)b*8388608u + (u32)h*65536u + (u32)(o-128)*128u; }
            #pragma unroll
            for (int nt = 0; nt < 4; ++nt) {
                int pl = nh + nt*16 + col;
                dst[pl] = f2bf(acc[mt][nt][r] + bb);
            }
        }
    }
}

// ---------------------------------------------------------------------------
// transpose_qk: 512 images (q then k, contiguous) [h][w] -> [w][h]
// ---------------------------------------------------------------------------
__global__ __launch_bounds__(256) void transpose_qk(u16* __restrict__ ws)
{
    __shared__ u16 tl[64][66];
    const int t = threadIdx.x;
    const int tile = blockIdx.x, img = blockIdx.y;
    const int h0 = (tile >> 1) * 64, w0 = (tile & 1) * 64;
    const u16* src = ws + WS_Q + (u32)img * HW_;
    u16* dst = ws + WS_QT + (u32)img * HW_;
    for (int e = t; e < 4096; e += 256) { int hl = e >> 6, wl = e & 63; tl[hl][wl] = src[(h0+hl)*W_ + w0 + wl]; }
    __syncthreads();
    for (int e = t; e < 4096; e += 256) { int wl = e >> 6, hl = e & 63; dst[(w0+wl)*H_ + h0 + hl] = tl[hl][wl]; }
}

// ---------------------------------------------------------------------------
// transpose_v: V [b][h][c][w] -> VT [b][c][w][h]. grid (4 tiles, 512 c, 4 b).
// ---------------------------------------------------------------------------
__global__ __launch_bounds__(256) void transpose_v(u16* __restrict__ ws)
{
    __shared__ u16 tl[64][66];
    const int t = threadIdx.x;
    const int tile = blockIdx.x, c = blockIdx.y, b = blockIdx.z;
    const int h0 = (tile >> 1) * 64, w0 = (tile & 1) * 64;
    const u16* src = ws + WS_V + (u32)b*8388608u + (u32)c*128u;   // + h*65536 + w
    u16* dst = ws + WS_VT + (u32)b*8388608u + (u32)c*16384u;      // + w*128 + h
    for (int e = t; e < 4096; e += 256) { int hl = e >> 6, wl = e & 63; tl[hl][wl] = src[(u32)(h0+hl)*65536u + w0 + wl]; }
    __syncthreads();
    for (int e = t; e < 4096; e += 256) { int wl = e >> 6, hl = e & 63; dst[(u32)(w0+wl)*128u + h0 + hl] = tl[hl][wl]; }
}

// shared LDS for hattn: q/k staging overlapped with softmaxed A
union __align__(16) ShAttn {
    struct QK { u16 q[128][72]; u16 kt[128][72]; } qk;  // 36864 B
    u16 a[128][136];                                    // 34816 B
};

// ---------------------------------------------------------------------------
// hattn: one block per (b,h). S[w1][w2]=sum_i q[w1][i]*kh[i][w2],
// kh[i][w2] = k[w2&63][2i+(w2>>6)].  ch[cc][w1]=sum_w2 A[w1][w2]*v[cc][w2].
// V in [b][h][c][w] -> A-operand fragments are 16B global loads within 4 KB.
// Writes raw ch (f32) -> d_out.
// ---------------------------------------------------------------------------
__global__ __launch_bounds__(256) void hattn_kernel(const u16* __restrict__ ws, float* __restrict__ outp)
{
    __shared__ ShAttn sh;
    const int t = threadIdx.x;
    const int h = blockIdx.x, b = blockIdx.y;
    const u16* qsrc = ws + WS_Q + (u32)(b*CQ_)*HW_ + h*W_;
    const u16* ksrc = ws + WS_K + (u32)(b*CQ_)*HW_ + h*W_;

    for (int e = t; e < 8192; e += 256) {
        int cq = e >> 7, w = e & 127;
        sh.qk.q[w][cq] = qsrc[cq*HW_ + w];
        u16 kv = ksrc[cq*HW_ + w];
        sh.qk.kt[cq + ((w & 1) << 6)][w >> 1] = kv;   // kt[w2][i] = kh[i][w2]
    }
    __syncthreads();

    const int wv = t >> 6, ln = t & 63, quad = ln >> 4, col = ln & 15;
    f32x4 accs[2][8];
    #pragma unroll
    for (int mt = 0; mt < 2; ++mt)
        #pragma unroll
        for (int nt = 0; nt < 8; ++nt) accs[mt][nt] = (f32x4){0.f,0.f,0.f,0.f};

    #pragma unroll
    for (int ks = 0; ks < 2; ++ks) {
        bf16x8 bfv[8];
        #pragma unroll
        for (int nt = 0; nt < 8; ++nt)
            bfv[nt] = *reinterpret_cast<const bf16x8*>(&sh.qk.kt[nt*16 + col][ks*32 + quad*8]);
        #pragma unroll
        for (int mt = 0; mt < 2; ++mt) {
            bf16x8 af = *reinterpret_cast<const bf16x8*>(&sh.qk.q[(wv*2 + mt)*16 + col][ks*32 + quad*8]);
            #pragma unroll
            for (int nt = 0; nt < 8; ++nt)
                accs[mt][nt] = __builtin_amdgcn_mfma_f32_16x16x32_bf16(af, bfv[nt], accs[mt][nt], 0, 0, 0);
        }
    }
    #pragma unroll
    for (int mt = 0; mt < 2; ++mt) {
        #pragma unroll
        for (int r = 0; r < 4; ++r) {
            float mx = accs[mt][0][r];
            #pragma unroll
            for (int nt = 1; nt < 8; ++nt) mx = fmaxf(mx, accs[mt][nt][r]);
            #pragma unroll
            for (int d = 1; d <= 8; d <<= 1) mx = fmaxf(mx, __shfl_xor(mx, d, 64));
            float sum = 0.f;
            #pragma unroll
            for (int nt = 0; nt < 8; ++nt) { float ev = __expf(accs[mt][nt][r] - mx); accs[mt][nt][r] = ev; sum += ev; }
            #pragma unroll
            for (int d = 1; d <= 8; d <<= 1) sum += __shfl_xor(sum, d, 64);
            float inv = 1.f / sum;
            #pragma unroll
            for (int nt = 0; nt < 8; ++nt) accs[mt][nt][r] *= inv;
        }
    }
    __syncthreads();
    #pragma unroll
    for (int mt = 0; mt < 2; ++mt)
        #pragma unroll
        for (int nt = 0; nt < 8; ++nt)
            #pragma unroll
            for (int r = 0; r < 4; ++r) {
                int w1 = (wv*2 + mt)*16 + quad*4 + r;
                int w2 = nt*16 + col;
                sh.a[w1][w2] = f2bf(accs[mt][nt][r]);
            }
    __syncthreads();

    const u16* vsrc = ws + WS_V + (u32)b*8388608u + (u32)h*65536u;   // [c][w], rows 128
    float* chout = outp + (u32)(b*C_)*HW_ + h*W_;
    const int ccw = wv * 128;
    for (int mp = 0; mp < 4; ++mp) {
        f32x4 accv[2][8];
        #pragma unroll
        for (int mi = 0; mi < 2; ++mi)
            #pragma unroll
            for (int nt = 0; nt < 8; ++nt) accv[mi][nt] = (f32x4){0.f,0.f,0.f,0.f};
        #pragma unroll
        for (int ks = 0; ks < 4; ++ks) {
            bf16x8 bfv[8];
            #pragma unroll
            for (int nt = 0; nt < 8; ++nt)
                bfv[nt] = *reinterpret_cast<const bf16x8*>(&sh.a[nt*16 + col][ks*32 + quad*8]);
            #pragma unroll
            for (int mi = 0; mi < 2; ++mi) {
                int cct = ccw + (mp*2 + mi)*16;
                bf16x8 af = *reinterpret_cast<const bf16x8*>(&vsrc[(u32)(cct + col)*128u + ks*32 + quad*8]);
                #pragma unroll
                for (int nt = 0; nt < 8; ++nt)
                    accv[mi][nt] = __builtin_amdgcn_mfma_f32_16x16x32_bf16(af, bfv[nt], accv[mi][nt], 0, 0, 0);
            }
        }
        #pragma unroll
        for (int mi = 0; mi < 2; ++mi)
            #pragma unroll
            for (int nt = 0; nt < 8; ++nt)
                #pragma unroll
                for (int r = 0; r < 4; ++r) {
                    int cc = ccw + (mp*2 + mi)*16 + quad*4 + r;
                    int w1 = nt*16 + col;
                    chout[(u32)cc*HW_ + w1] = accv[mi][nt][r];
                }
    }
}

// LDS for vattn: qk staging / (A + V-chunk)
// vld stride 144 u16 (288 B = 8 banks mod 32): quads land on disjoint bank
// octets for the scalar fragment gathers -> only free 2-way conflicts.
union __align__(16) ShV {
    struct QK { u16 q[128][72]; u16 kt[128][72]; } qk;     // 36864 B
    struct PV { u16 a[128][136]; u16 vld[128][144]; } pv;  // 71680 B
};

// ---------------------------------------------------------------------------
// vattn: one block per (b,w). qv[h1][i]=qT[h1>>1][w][64*(h1&1)+i];
// kv[i][h2]=kT[i][w][h2]; vv[h2][cc]=VT[4*h2+(cc>>7)][w][cc&127].
// V-chunk (cc>>7 == mp) staged to LDS coalesced (FIX: full 128x128 coverage).
// Writes cv^T [b][cc][w][h1] bf16 -> WS_CV.
// ---------------------------------------------------------------------------
__global__ __launch_bounds__(256) void vattn_kernel(u16* __restrict__ ws)
{
    __shared__ ShV sh;
    const int t = threadIdx.x;
    const int w = blockIdx.x, b = blockIdx.y;
    const u16* qTs = ws + WS_QT + (u32)(b*CQ_)*HW_ + w*H_;
    const u16* kTs = ws + WS_KT + (u32)(b*CQ_)*HW_ + w*H_;

    for (int e = t; e < 8192; e += 256) {
        int cq = e >> 7, hh = e & 127;
        sh.qk.q[2*cq + (hh >> 6)][hh & 63] = qTs[cq*HW_ + hh];
        sh.qk.kt[hh][cq] = kTs[cq*HW_ + hh];
    }
    __syncthreads();

    const int wv = t >> 6, ln = t & 63, quad = ln >> 4, col = ln & 15;
    f32x4 accs[2][8];
    #pragma unroll
    for (int mt = 0; mt < 2; ++mt)
        #pragma unroll
        for (int nt = 0; nt < 8; ++nt) accs[mt][nt] = (f32x4){0.f,0.f,0.f,0.f};

    #pragma unroll
    for (int ks = 0; ks < 2; ++ks) {
        bf16x8 bfv[8];
        #pragma unroll
        for (int nt = 0; nt < 8; ++nt)
            bfv[nt] = *reinterpret_cast<const bf16x8*>(&sh.qk.kt[nt*16 + col][ks*32 + quad*8]);
        #pragma unroll
        for (int mt = 0; mt < 2; ++mt) {
            bf16x8 af = *reinterpret_cast<const bf16x8*>(&sh.qk.q[(wv*2 + mt)*16 + col][ks*32 + quad*8]);
            #pragma unroll
            for (int nt = 0; nt < 8; ++nt)
                accs[mt][nt] = __builtin_amdgcn_mfma_f32_16x16x32_bf16(af, bfv[nt], accs[mt][nt], 0, 0, 0);
        }
    }
    #pragma unroll
    for (int mt = 0; mt < 2; ++mt) {
        #pragma unroll
        for (int r = 0; r < 4; ++r) {
            float mx = accs[mt][0][r];
            #pragma unroll
            for (int nt = 1; nt < 8; ++nt) mx = fmaxf(mx, accs[mt][nt][r]);
            #pragma unroll
            for (int d = 1; d <= 8; d <<= 1) mx = fmaxf(mx, __shfl_xor(mx, d, 64));
            float sum = 0.f;
            #pragma unroll
            for (int nt = 0; nt < 8; ++nt) { float ev = __expf(accs[mt][nt][r] - mx); accs[mt][nt][r] = ev; sum += ev; }
            #pragma unroll
            for (int d = 1; d <= 8; d <<= 1) sum += __shfl_xor(sum, d, 64);
            float inv = 1.f / sum;
            #pragma unroll
            for (int nt = 0; nt < 8; ++nt) accs[mt][nt][r] *= inv;
        }
    }
    __syncthreads();
    #pragma unroll
    for (int mt = 0; mt < 2; ++mt)
        #pragma unroll
        for (int nt = 0; nt < 8; ++nt)
            #pragma unroll
            for (int r = 0; r < 4; ++r) {
                int h1 = (wv*2 + mt)*16 + quad*4 + r;
                int h2 = nt*16 + col;
                sh.pv.a[h1][h2] = f2bf(accs[mt][nt][r]);
            }
    __syncthreads();

    const u32 vtb = WS_VT + (u32)b*8388608u + (u32)w*128u;   // + c*16384 + h
    u16* cvout = ws + WS_CV + (u32)(b*C_)*HW_ + (u32)w*H_;   // + cc*HW + h1
    for (int mp = 0; mp < 4; ++mp) {
        if (mp) __syncthreads();
        // stage vld[h2][h] = VT[4*h2+mp][w][h] : 128 rows x 128 h = 16384 elems
        // = 2048 uint4; 8 passes x 256 thr. 16 consecutive threads read one
        // contiguous 256 B row (coalesced).
        #pragma unroll
        for (int pass = 0; pass < 8; ++pass) {
            int ci = pass*256 + t, h2 = ci >> 4, kj = ci & 15;
            uint4 d = *reinterpret_cast<const uint4*>(ws + vtb + (u32)(4*h2 + mp)*16384u + kj*8);
            *reinterpret_cast<uint4*>(&sh.pv.vld[h2][kj*8]) = d;
        }
        __syncthreads();
        f32x4 accv[2][8];
        #pragma unroll
        for (int mi = 0; mi < 2; ++mi)
            #pragma unroll
            for (int nt = 0; nt < 8; ++nt) accv[mi][nt] = (f32x4){0.f,0.f,0.f,0.f};
        #pragma unroll
        for (int ks = 0; ks < 4; ++ks) {
            bf16x8 bfv[8];
            #pragma unroll
            for (int nt = 0; nt < 8; ++nt)
                bfv[nt] = *reinterpret_cast<const bf16x8*>(&sh.pv.a[nt*16 + col][ks*32 + quad*8]);
            #pragma unroll
            for (int mi = 0; mi < 2; ++mi) {
                const int clo = wv*32 + mi*16;
                BF8 af;
                #pragma unroll
                for (int jj = 0; jj < 8; ++jj)
                    af.s[jj] = sh.pv.vld[ks*32 + quad*8 + jj][clo + col];
                #pragma unroll
                for (int nt = 0; nt < 8; ++nt)
                    accv[mi][nt] = __builtin_amdgcn_mfma_f32_16x16x32_bf16(af.v, bfv[nt], accv[mi][nt], 0, 0, 0);
            }
        }
        #pragma unroll
        for (int mi = 0; mi < 2; ++mi)
            #pragma unroll
            for (int nt = 0; nt < 8; ++nt)
                #pragma unroll
                for (int r = 0; r < 4; ++r) {
                    int cc = mp*128 + wv*32 + mi*16 + quad*4 + r;
                    int h1 = nt*16 + col;
                    cvout[(u32)cc*HW_ + h1] = f2bf(accv[mi][nt][r]);
                }
    }
}

// ---------------------------------------------------------------------------
// combine: out = gamma*(ch + cv) + x ; ch f32 in d_out, cv bf16 [b][c][w][h] in ws
// ---------------------------------------------------------------------------
__global__ __launch_bounds__(256) void combine_kernel(const u16* __restrict__ ws, const float* __restrict__ x,
                                                      const float* __restrict__ gamma, float* __restrict__ outp)
{
    __shared__ u16 tl[64][66];
    const int t = threadIdx.x;
    const int tile = blockIdx.x, cc = blockIdx.y, b = blockIdx.z;
    const int h0 = (tile >> 1) * 64, w0 = (tile & 1) * 64;
    const float g = gamma[0];
    const u32 base = ((u32)(b*C_) + cc) * HW_;
    const u16* cvs = ws + WS_CV + base;
    for (int e = t; e < 4096; e += 256) { int wl = e >> 6, hl = e & 63; tl[wl][hl] = cvs[(w0+wl)*H_ + h0 + hl]; }
    __syncthreads();
    for (int e = t; e < 4096; e += 256) {
        int hl = e >> 6, wl = e & 63;
        u32 idx = base + (h0+hl)*W_ + w0 + wl;
        float cv = bf2f(tl[wl][hl]);
        float ch = outp[idx];
        outp[idx] = g * (ch + cv) + x[idx];
    }
}

extern "C" void kernel_launch(void* const* d_in, const int* in_sizes, int n_in,
                              void* d_out, int out_size, void* d_ws, size_t ws_size,
                              hipStream_t stream)
{
    const float* x  = (const float*)d_in[0];
    const float* Wq = (const float*)d_in[1];
    const float* bq = (const float*)d_in[2];
    const float* Wk = (const float*)d_in[3];
    const float* bk = (const float*)d_in[4];
    const float* Wv = (const float*)d_in[5];
    const float* bv = (const float*)d_in[6];
    const float* gm = (const float*)d_in[7];
    float* out = (float*)d_out;
    u16* ws  = (u16*)d_ws;

    prep_x<<<dim3(256, 8, 4), 256, 0, stream>>>(x, ws);
    prep_w<<<dim3(320), 256, 0, stream>>>(Wq, Wk, Wv, ws);
    proj_kernel<<<dim3(5, 128, 4), 256, 0, stream>>>(bq, bk, bv, ws);
    transpose_qk<<<dim3(4, 512), 256, 0, stream>>>(ws);
    transpose_v<<<dim3(4, 512, 4), 256, 0, stream>>>(ws);
    hattn_kernel<<<dim3(128, 4), 256, 0, stream>>>(ws, out);
    vattn_kernel<<<dim3(128, 4), 256, 0, stream>>>(ws);
    combine_kernel<<<dim3(4, 512, 4), 256, 0, stream>>>(ws, x, gm, out);
}